// Round 1
// baseline (828.175 us; speedup 1.0000x reference)
//
#include <hip/hip_runtime.h>

// SJLT projection: out[b, idx[d,j]] += x[b,d] * sign(d,j), * 1/sqrt(4)
// B=64, D=524288, P=8192, C=4.
//
// Strategy: LDS-privatized scatter. Each block owns BT=4 batch rows and a
// 32768-wide D-chunk; accumulates into a 4x8192 fp32 LDS accumulator
// (128 KiB), then flushes *0.5 to global with native f32 atomics.
// Grid = 16 chunks x 16 row-groups = 256 blocks = 1/CU.

constexpr int BATCH  = 64;
constexpr int DIM    = 524288;
constexpr int PROJ   = 8192;

constexpr int BT      = 4;                 // batch rows per block
constexpr int BLOCK   = 1024;              // threads per block (16 waves)
constexpr int DCHUNKS = 16;
constexpr int CHUNK   = DIM / DCHUNKS;     // 32768, divisible by BLOCK
constexpr int ROWG    = BATCH / BT;        // 16

__global__ __launch_bounds__(BLOCK) void sjlt_scatter(
    const float* __restrict__ x,
    const int4*  __restrict__ idx4,   // (DIM) rows of 4 int32 indices
    const int4*  __restrict__ sgn4,   // (DIM) rows of 4 int32 {0,1}
    float*       __restrict__ out)
{
    __shared__ float acc[BT * PROJ];  // 128 KiB

    for (int i = threadIdx.x; i < BT * PROJ; i += BLOCK) acc[i] = 0.0f;
    __syncthreads();

    const int rg   = blockIdx.y;
    const int row0 = rg * BT;
    const int dbeg = blockIdx.x * CHUNK;

    const float* __restrict__ xr0 = x + (size_t)(row0 + 0) * DIM;
    const float* __restrict__ xr1 = x + (size_t)(row0 + 1) * DIM;
    const float* __restrict__ xr2 = x + (size_t)(row0 + 2) * DIM;
    const float* __restrict__ xr3 = x + (size_t)(row0 + 3) * DIM;

    for (int d = dbeg + (int)threadIdx.x; d < dbeg + CHUNK; d += BLOCK) {
        const int4 iv = idx4[d];
        const int4 sv = sgn4[d];
        const float x0 = xr0[d];
        const float x1 = xr1[d];
        const float x2 = xr2[d];
        const float x3 = xr3[d];

        const int p[4] = {iv.x, iv.y, iv.z, iv.w};
        const int s[4] = {sv.x, sv.y, sv.z, sv.w};
#pragma unroll
        for (int j = 0; j < 4; ++j) {
            const bool pos = (s[j] != 0);
            float* a = &acc[p[j]];
            unsafeAtomicAdd(a + 0 * PROJ, pos ? x0 : -x0);
            unsafeAtomicAdd(a + 1 * PROJ, pos ? x1 : -x1);
            unsafeAtomicAdd(a + 2 * PROJ, pos ? x2 : -x2);
            unsafeAtomicAdd(a + 3 * PROJ, pos ? x3 : -x3);
        }
    }
    __syncthreads();

    // flush: scale by 1/sqrt(4) = 0.5; 16 chunk-blocks contribute per output
    for (int i = threadIdx.x; i < BT * PROJ; i += BLOCK) {
        const int r = i >> 13;          // i / PROJ
        const int pp = i & (PROJ - 1);  // i % PROJ
        unsafeAtomicAdd(&out[(size_t)(row0 + r) * PROJ + pp], acc[i] * 0.5f);
    }
}

extern "C" void kernel_launch(void* const* d_in, const int* in_sizes, int n_in,
                              void* d_out, int out_size, void* d_ws, size_t ws_size,
                              hipStream_t stream) {
    const float* x   = (const float*)d_in[0];
    const int4*  idx = (const int4*) d_in[1];
    const int4*  sgn = (const int4*) d_in[2];
    float*       out = (float*)d_out;

    // harness re-poisons d_out to 0xAA before every launch -> zero it
    hipMemsetAsync(d_out, 0, (size_t)out_size * sizeof(float), stream);

    dim3 grid(DCHUNKS, ROWG);
    sjlt_scatter<<<grid, BLOCK, 0, stream>>>(x, idx, sgn, out);
}